// Round 6
// baseline (165.555 us; speedup 1.0000x reference)
//
#include <hip/hip_runtime.h>
#include <hip/hip_bf16.h>

typedef unsigned short u16;
typedef short bf16x8 __attribute__((ext_vector_type(8)));
typedef float f32x4 __attribute__((ext_vector_type(4)));

__device__ __forceinline__ u16 f2bf(float f){
    unsigned u = __float_as_uint(f);
    unsigned r = 0x7fffu + ((u >> 16) & 1u);
    return (u16)((u + r) >> 16);
}
__device__ __forceinline__ float bf2f(u16 h){
    return __uint_as_float(((unsigned)h) << 16);
}

// async global->LDS, 16B per lane; LDS dest = wave-uniform base + lane*16
__device__ __forceinline__ void gload_lds16(const u16* g, u16* lds_base){
    __builtin_amdgcn_global_load_lds(
        (const __attribute__((address_space(1))) unsigned int*)g,
        (__attribute__((address_space(3))) unsigned int*)lds_base, 16, 0, 0);
}

// raw workgroup barrier WITHOUT the vmcnt(0) drain __syncthreads would emit;
// empty asm = compiler-only fence so LDS ops can't be moved across it.
__device__ __forceinline__ void wgbar(){
    asm volatile("" ::: "memory");
    __builtin_amdgcn_s_barrier();
    asm volatile("" ::: "memory");
}

// ---------------- problem constants ----------------
// Inputs f32 (targets i32): noise(2,768,577) targets(2,384,384) w1(512,768,3,3)
// b1(512) w2(512,512,3,3) b2(512) w3(77) b3(77)
// Outputs f32: out0 (577,2,768)=886272 ; out1 (2,77,171,512)=13483008
#define OUT0_N 886272
#define OUT1_N 13483008
#define YN 175104           // 342*512
#define KS2 12              // gemm2 K-split: 4608/12 = 384 per chunk

// ---------------- fused prep ----------------
// blocks: trans(912) | prepA(1536) | Mfull16+biaspart(1024) | labels(5) | Zcat pad zero(756)
__global__ void k_prep(const float* __restrict__ noise, const int* __restrict__ targets,
                       const float* __restrict__ w1, const float* __restrict__ b1,
                       const float* __restrict__ w2,
                       float* __restrict__ out0, u16* __restrict__ XbfT,
                       u16* __restrict__ Are, u16* __restrict__ Mfull16,
                       float* __restrict__ biasH, int* __restrict__ labels,
                       u16* __restrict__ Zcat16){
    __shared__ float sh[32 * 33];
    int blk = blockIdx.x;
    int tid = threadIdx.x;
    if (blk < 912){
        int b   = blk / 456;           // 19*24
        int rem = blk % 456;
        int cb  = rem / 19, sb = rem % 19;
        int tx = tid & 31, ty = tid >> 5;      // 32 x 8
        int s0 = sb * 32, c0 = cb * 32;
        float (*tile)[33] = (float(*)[33])sh;
        #pragma unroll
        for (int i = 0; i < 4; i++){
            int c = c0 + ty + i * 8;
            int s = s0 + tx;
            if (s < 577) tile[ty + i * 8][tx] = noise[(size_t)(b * 768 + c) * 577 + s];
        }
        __syncthreads();
        #pragma unroll
        for (int i = 0; i < 4; i++){
            int s = s0 + ty + i * 8;
            int c = c0 + tx;
            if (s >= 577) continue;
            float v = tile[tx][ty + i * 8];
            out0[(size_t)(s * 2 + b) * 768 + c] = v;
            if (s >= 1) XbfT[(size_t)(b * 576 + s - 1) * 768 + c] = f2bf(v);
        }
    } else if (blk < 2448){
        int idx = (blk - 912) * 256 + tid;     // < 512*768
        int k = idx % 768; int c1 = idx / 768;
        const float* wp = w1 + (size_t)idx * 9;
        #pragma unroll
        for (int tap = 0; tap < 9; tap++)
            Are[(size_t)(c1 * 9 + tap) * 768 + k] = f2bf(wp[tap]);
    } else if (blk < 3472){
        // Mfull16 + bias partial: block b2i = blk-2448 covers c2 = b2i>>1, c1-half h = b2i&1
        int b2i = blk - 2448;
        int c2 = b2i >> 1, h = b2i & 1;
        int c1 = h * 256 + tid;
        const float* wp = w2 + (size_t)(c2 * 512 + c1) * 9;
        float t[3][3];
        #pragma unroll
        for (int r = 0; r < 3; r++)
            #pragma unroll
            for (int s = 0; s < 3; s++)
                t[r][s] = wp[r * 3 + s];
        float cs0[3], cs1[3], cs2[3];
        #pragma unroll
        for (int r = 0; r < 3; r++){
            cs0[r] = t[r][0] + t[r][1];
            cs1[r] = t[r][0] + t[r][1] + t[r][2];
            cs2[r] = t[r][1] + t[r][2];
        }
        const float inv = 1.0f / 576.0f;
        u16* Mp = Mfull16 + (size_t)(c2 * 512 + c1) * 9;
        Mp[0] = f2bf(inv * (cs0[0] + cs0[1]));
        Mp[1] = f2bf(inv * (cs1[0] + cs1[1]));
        Mp[2] = f2bf(inv * (cs2[0] + cs2[1]));
        Mp[3] = f2bf(inv * (cs0[0] + cs0[1] + cs0[2]));
        Mp[4] = f2bf(inv * (cs1[0] + cs1[1] + cs1[2]));
        Mp[5] = f2bf(inv * (cs2[0] + cs2[1] + cs2[2]));
        Mp[6] = f2bf(inv * (cs0[1] + cs0[2]));
        Mp[7] = f2bf(inv * (cs1[1] + cs1[2]));
        Mp[8] = f2bf(inv * (cs2[1] + cs2[2]));
        // bias partial: sum_{c1 in half} b1[c1] * (sum_q w2[q]*cw[q]) / 36
        float s_cw = 25.f * (t[0][0] + t[0][2] + t[2][0] + t[2][2])
                   + 30.f * (t[0][1] + t[1][0] + t[1][2] + t[2][1])
                   + 36.f * t[1][1];
        sh[tid] = b1[c1] * s_cw;
        __syncthreads();
        for (int o = 128; o > 0; o >>= 1){ if (tid < o) sh[tid] += sh[tid + o]; __syncthreads(); }
        if (tid == 0) biasH[h * 512 + c2] = sh[0] * (1.0f / 36.0f);
    } else if (blk < 3477){
        int idx = (blk - 3472) * 256 + tid;
        if (idx < 1152){
            int b = idx / 576; int p = idx % 576;
            int i = p / 24, j = p % 24;
            labels[idx] = targets[b * 147456 + i * 16 * 384 + j * 16];
        }
    } else {
        // zero Zcat pad rows 342..383 (42*4608 = 193536 u16)
        int idx = (blk - 3477) * 256 + tid;
        if (idx < 193536) Zcat16[342 * 4608 + idx] = 0;
    }
}

// ---------------- GEMM1 v3: 192x128 tile, LDS double-buffer, counted vmcnt, XOR-swizzle ----
// D[4608][1152] (bf16) = Are * XbfT^T.  Grid (24,9) = 216 blocks, single dispatch round.
// Swizzle (T2, rule #21): pre-swizzled global source, linear LDS dest, same XOR on read.
// Pipeline (T3/T4 minimum form): stage(t+1) before compute(t); counted vmcnt, raw s_barrier.
// NO setprio here: 2-barrier lockstep regime, T5 measured negative (m190).
__launch_bounds__(256)
__global__ void k_gemm1(const u16* __restrict__ Are, const u16* __restrict__ XbfT,
                        u16* __restrict__ D){
    __shared__ u16 As[2][192 * 64];   // 24 KB x2
    __shared__ u16 Bs[2][128 * 64];   // 16 KB x2  (total 80 KB -> 2 blocks/CU)
    int tid  = threadIdx.x;
    int wave = tid >> 6, lane = tid & 63;
    int l16 = lane & 15, quad = lane >> 4;
    int wm = wave >> 1, wn = wave & 1;      // 2x2 waves; wave-tile 96x64
    int m0 = blockIdx.x * 192;
    int n0 = blockIdx.y * 128;
    int srow = lane >> 3;                           // 0..7 (row within 8-row chunk)
    int scol = ((lane & 7) * 8) ^ (srow * 8);       // pre-swizzled source col (u16 units)
    int rx   = (l16 & 7) * 8;                       // read-side XOR
    const u16* Ag = Are  + (size_t)(m0 + srow) * 768 + scol;
    const u16* Bg = XbfT + (size_t)(n0 + srow) * 768 + scol;
    f32x4 acc[6][4] = {};

    auto stage = [&](int buf, int k0){
        #pragma unroll
        for (int j = 0; j < 6; j++){
            int ch = wave * 6 + j;                  // 24 A-chunks of 8 rows
            gload_lds16(Ag + (size_t)ch * 8 * 768 + k0, &As[buf][ch * 512]);
        }
        #pragma unroll
        for (int j = 0; j < 4; j++){
            int ch = wave * 4 + j;                  // 16 B-chunks of 8 rows
            gload_lds16(Bg + (size_t)ch * 8 * 768 + k0, &Bs[buf][ch * 512]);
        }
    };
    auto compute = [&](int buf){
        #pragma unroll
        for (int ks = 0; ks < 2; ks++){
            int kc = (ks * 32 + quad * 8) ^ rx;
            bf16x8 af[6], bf[4];
            #pragma unroll
            for (int i = 0; i < 6; i++)
                af[i] = *(const bf16x8*)&As[buf][(wm * 96 + i * 16 + l16) * 64 + kc];
            #pragma unroll
            for (int i = 0; i < 4; i++)
                bf[i] = *(const bf16x8*)&Bs[buf][(wn * 64 + i * 16 + l16) * 64 + kc];
            #pragma unroll
            for (int mi = 0; mi < 6; mi++)
                #pragma unroll
                for (int ni = 0; ni < 4; ni++)
                    acc[mi][ni] = __builtin_amdgcn_mfma_f32_16x16x32_bf16(af[mi], bf[ni], acc[mi][ni], 0, 0, 0);
        }
    };

    stage(0, 0);
    #pragma unroll 1
    for (int t = 0; t < 10; t += 2){
        stage(1, (t + 1) * 64);
        asm volatile("s_waitcnt vmcnt(10)" ::: "memory");
        wgbar();
        compute(0);
        wgbar();
        stage(0, (t + 2) * 64);
        asm volatile("s_waitcnt vmcnt(10)" ::: "memory");
        wgbar();
        compute(1);
        wgbar();
    }
    stage(1, 11 * 64);
    asm volatile("s_waitcnt vmcnt(10)" ::: "memory");
    wgbar();
    compute(0);                 // K-step 10
    wgbar();
    asm volatile("s_waitcnt vmcnt(0)" ::: "memory");
    wgbar();
    compute(1);                 // K-step 11

    #pragma unroll
    for (int mi = 0; mi < 6; mi++)
        #pragma unroll
        for (int ni = 0; ni < 4; ni++)
            #pragma unroll
            for (int r = 0; r < 4; r++)
                D[(size_t)(m0 + wm * 96 + mi * 16 + quad * 4 + r) * 1152 + n0 + wn * 64 + ni * 16 + l16] = f2bf(acc[mi][ni][r]);
}

// ---------------- scatter: one block per (b,c1); LDS class-histogram; bf16 in/out --------
__launch_bounds__(256)
__global__ void k_scatter(const u16* __restrict__ D, const int* __restrict__ labels,
                          u16* __restrict__ Zcat16){
    int blk = blockIdx.x;            // 0..1023
    int b  = blk >> 9;
    int c1 = blk & 511;
    __shared__ float acc[171 * 9];
    int t = threadIdx.x;
    for (int q = t; q < 1539; q += 256) acc[q] = 0.f;
    __syncthreads();
    for (int p = t; p < 576; p += 256){
        int cls = labels[b * 576 + p];
        if (cls < 0 || cls >= 171) continue;
        int i = p / 24, j = p % 24;
        float slot[9];
        #pragma unroll
        for (int q = 0; q < 9; q++) slot[q] = 0.f;
        unsigned used = 0;
        int tau[3]; bool vs[3];
        #pragma unroll
        for (int s1 = 0; s1 < 3; s1++){
            int v = j - s1 + 1;
            vs[s1]  = (v >= 0 && v < 24);
            tau[s1] = (v < 4) ? 0 : ((v < 20) ? 1 : 2);
        }
        #pragma unroll
        for (int r1 = 0; r1 < 3; r1++){
            int u = i - r1 + 1;
            if (u < 0 || u >= 24) continue;
            int rho = (u < 4) ? 0 : ((u < 20) ? 1 : 2);
            #pragma unroll
            for (int s1 = 0; s1 < 3; s1++){
                if (!vs[s1]) continue;
                float tv = bf2f(D[(size_t)(c1 * 9 + r1 * 3 + s1) * 1152 + b * 576 + p]);
                int sl = rho * 3 + tau[s1];
                slot[sl] += tv;
                used |= 1u << sl;
            }
        }
        #pragma unroll
        for (int sl = 0; sl < 9; sl++)
            if (used & (1u << sl)) atomicAdd(&acc[cls * 9 + sl], slot[sl]);
    }
    __syncthreads();
    for (int q = t; q < 1539; q += 256){
        int cls = q / 9, sl = q % 9;
        Zcat16[(size_t)(b * 171 + cls) * 4608 + c1 * 9 + sl] = f2bf(acc[q]);
    }
}

// ---------------- GEMM2 (LDS-staged MFMA, K-split): ypart[s][n][c2] ----------------
// A = Zcat16[384][4608] (rows n, 128-tile), B = Mfull16[512][4608] (rows c2, 64-tile).
// Output rows = n, cols = c2 -> coalesced stores. Grid (3, 8, KS2), K-chunk 384.
// Deterministic ypart (R4's atomic variant measured +4.3 us).
__launch_bounds__(256)
__global__ void k_gemm2m(const u16* __restrict__ Zcat16, const u16* __restrict__ Mfull16,
                         float* __restrict__ ypart){
    __shared__ u16 As[128 * 64];   // [n][k]
    __shared__ u16 Bs[64 * 64];    // [c2][k]
    int tid  = threadIdx.x;
    int wave = tid >> 6, lane = tid & 63;
    int l16 = lane & 15, quad = lane >> 4;
    int wm = wave >> 1, wn = wave & 1;
    int m0 = blockIdx.x * 128;          // n
    int n0 = blockIdx.y * 64;           // c2
    int kbeg = blockIdx.z * 384;
    int srow = lane >> 3, scol = (lane & 7) * 8;
    f32x4 acc[4][2] = {};
    for (int k0 = kbeg; k0 < kbeg + 384; k0 += 64){
        #pragma unroll
        for (int j = 0; j < 4; j++){
            int ch = wave * 4 + j;
            gload_lds16(Zcat16 + (size_t)(m0 + ch * 8 + srow) * 4608 + k0 + scol, &As[ch * 512]);
        }
        #pragma unroll
        for (int j = 0; j < 2; j++){
            int ch = wave * 2 + j;
            gload_lds16(Mfull16 + (size_t)(n0 + ch * 8 + srow) * 4608 + k0 + scol, &Bs[ch * 512]);
        }
        __syncthreads();
        #pragma unroll
        for (int ks = 0; ks < 2; ks++){
            bf16x8 af[4], bf[2];
            #pragma unroll
            for (int i = 0; i < 4; i++)
                af[i] = *(const bf16x8*)&As[(wm * 64 + i * 16 + l16) * 64 + ks * 32 + quad * 8];
            #pragma unroll
            for (int i = 0; i < 2; i++)
                bf[i] = *(const bf16x8*)&Bs[(wn * 32 + i * 16 + l16) * 64 + ks * 32 + quad * 8];
            #pragma unroll
            for (int mi = 0; mi < 4; mi++)
                #pragma unroll
                for (int ni = 0; ni < 2; ni++)
                    acc[mi][ni] = __builtin_amdgcn_mfma_f32_16x16x32_bf16(af[mi], bf[ni], acc[mi][ni], 0, 0, 0);
        }
        __syncthreads();
    }
    float* yp = ypart + (size_t)blockIdx.z * YN;
    #pragma unroll
    for (int mi = 0; mi < 4; mi++)
        #pragma unroll
        for (int r = 0; r < 4; r++){
            int n = m0 + wm * 64 + mi * 16 + quad * 4 + r;
            if (n >= 342) continue;
            #pragma unroll
            for (int ni = 0; ni < 2; ni++)
                yp[(size_t)n * 512 + n0 + wn * 32 + ni * 16 + l16] = acc[mi][ni][r];
        }
}

// ---------------- fused reduce+expand: out1[b,o,cls,c] = w3[o]*(bias+sum_s ypart) + b3[o] ----
// block = (pair = b*171+cls, o-half); 684 blocks x 128 threads (c4).
// Each thread computes the 12-term K-split sum ONCE (identical f32 order to the old
// k_red: b2 + biasH[0] + biasH[1] + s-loop -> bit-identical out1), then streams its
// ~39 coalesced float4 stores. Removes the k_red dispatch + ysum round-trip.
__global__ void k_expand(const float* __restrict__ ypart, const float* __restrict__ biasH,
                         const float* __restrict__ b2, const float* __restrict__ w3,
                         const float* __restrict__ b3, float4* __restrict__ out1){
    __shared__ float w3s[77], b3s[77];
    int tid = threadIdx.x;                 // 0..127 = c4
    if (tid < 77){ w3s[tid] = w3[tid]; b3s[tid] = b3[tid]; }
    __syncthreads();
    int blk  = blockIdx.x;                 // 0..683
    int pair = blk >> 1;                   // b*171 + cls
    int oh   = blk & 1;
    int b    = pair / 171, cls = pair % 171;
    float4 sum = ((const float4*)b2)[tid];
    float4 ba  = ((const float4*)biasH)[tid];
    float4 bb  = ((const float4*)biasH)[128 + tid];
    sum.x += ba.x + bb.x; sum.y += ba.y + bb.y; sum.z += ba.z + bb.z; sum.w += ba.w + bb.w;
    #pragma unroll
    for (int s = 0; s < KS2; s++){
        float4 v = *(const float4*)&ypart[(size_t)s * YN + (size_t)pair * 512 + tid * 4];
        sum.x += v.x; sum.y += v.y; sum.z += v.z; sum.w += v.w;
    }
    int obeg = oh ? 39 : 0;
    int oend = oh ? 77 : 39;
    size_t base = ((size_t)b * 77 * 171 + cls) * 128 + tid;
    for (int o = obeg; o < oend; o++){
        float w = w3s[o], bo = b3s[o];
        out1[base + (size_t)o * 171 * 128] =
            make_float4(w * sum.x + bo, w * sum.y + bo, w * sum.z + bo, w * sum.w + bo);
    }
}

extern "C" void kernel_launch(void* const* d_in, const int* in_sizes, int n_in,
                              void* d_out, int out_size, void* d_ws, size_t ws_size,
                              hipStream_t stream) {
    const float* noise   = (const float*)d_in[0];
    const int*   targets = (const int*)  d_in[1];
    const float* w1      = (const float*)d_in[2];
    const float* b1      = (const float*)d_in[3];
    const float* w2      = (const float*)d_in[4];
    const float* b2      = (const float*)d_in[5];
    const float* w3      = (const float*)d_in[6];
    const float* b3      = (const float*)d_in[7];
    float* out0 = (float*)d_out;
    float* out1 = out0 + OUT0_N;

    char* ws = (char*)d_ws;
    const size_t OFF_ARE  = 0;                        // 4608*768*2   = 7,077,888
    const size_t OFF_X    = 7077888;                  // 1152*768*2   = 1,769,472
    const size_t OFF_D    = OFF_X   + 1769472;        // 4608*1152*2  = 10,616,832 (bf16; alias ypart 8,404,992)
    const size_t OFF_MF   = OFF_D   + 10616832;       // 512*4608*2   = 4,718,592
    const size_t OFF_ZC   = OFF_MF  + 4718592;        // 384*4608*2   = 3,538,944
    const size_t OFF_BH   = OFF_ZC  + 3538944;        // 2*512*4 = 4096
    const size_t OFF_LAB  = OFF_BH  + 4096;           // 4608

    u16*   Are    = (u16*)  (ws + OFF_ARE);
    u16*   XbfT   = (u16*)  (ws + OFF_X);
    u16*   D      = (u16*)  (ws + OFF_D);
    float* ypart  = (float*)(ws + OFF_D);             // alias: D dead after k_scatter; 8.4MB <= 10.6MB
    u16*   Mfull16= (u16*)  (ws + OFF_MF);
    u16*   Zcat16 = (u16*)  (ws + OFF_ZC);
    float* biasH  = (float*)(ws + OFF_BH);
    int*   labels = (int*)  (ws + OFF_LAB);

    k_prep  <<<4233, 256, 0, stream>>>(noise, targets, w1, b1, w2,
                                       out0, XbfT, Are, Mfull16, biasH, labels, Zcat16);
    k_gemm1 <<<dim3(24, 9), 256, 0, stream>>>(Are, XbfT, D);
    k_scatter<<<1024, 256, 0, stream>>>(D, labels, Zcat16);
    k_gemm2m<<<dim3(3, 8, KS2), 256, 0, stream>>>(Zcat16, Mfull16, ypart);
    k_expand<<<684, 128, 0, stream>>>(ypart, biasH, b2, w3, b3, (float4*)out1);
}

// Round 7
// 155.639 us; speedup vs baseline: 1.0637x; 1.0637x over previous
//
#include <hip/hip_runtime.h>
#include <hip/hip_bf16.h>

typedef unsigned short u16;
typedef short bf16x8 __attribute__((ext_vector_type(8)));
typedef float f32x4 __attribute__((ext_vector_type(4)));

__device__ __forceinline__ u16 f2bf(float f){
    unsigned u = __float_as_uint(f);
    unsigned r = 0x7fffu + ((u >> 16) & 1u);
    return (u16)((u + r) >> 16);
}
__device__ __forceinline__ float bf2f(u16 h){
    return __uint_as_float(((unsigned)h) << 16);
}

// async global->LDS, 16B per lane; LDS dest = wave-uniform base + lane*16
__device__ __forceinline__ void gload_lds16(const u16* g, u16* lds_base){
    __builtin_amdgcn_global_load_lds(
        (const __attribute__((address_space(1))) unsigned int*)g,
        (__attribute__((address_space(3))) unsigned int*)lds_base, 16, 0, 0);
}

// raw workgroup barrier WITHOUT the vmcnt(0) drain __syncthreads would emit;
// empty asm = compiler-only fence so LDS ops can't be moved across it.
__device__ __forceinline__ void wgbar(){
    asm volatile("" ::: "memory");
    __builtin_amdgcn_s_barrier();
    asm volatile("" ::: "memory");
}

// ---------------- problem constants ----------------
// Inputs f32 (targets i32): noise(2,768,577) targets(2,384,384) w1(512,768,3,3)
// b1(512) w2(512,512,3,3) b2(512) w3(77) b3(77)
// Outputs f32: out0 (577,2,768)=886272 ; out1 (2,77,171,512)=13483008
#define OUT0_N 886272
#define OUT1_N 13483008
#define YN 175104           // 342*512
#define KS2 12              // gemm2 K-split: 4608/12 = 384 per chunk

// ---------------- fused prep ----------------
// blocks: trans(912) | prepA(1536) | Mfull16+biaspart(1024) | labels(5) | Zcat pad zero(756)
__global__ void k_prep(const float* __restrict__ noise, const int* __restrict__ targets,
                       const float* __restrict__ w1, const float* __restrict__ b1,
                       const float* __restrict__ w2,
                       float* __restrict__ out0, u16* __restrict__ XbfT,
                       u16* __restrict__ Are, u16* __restrict__ Mfull16,
                       float* __restrict__ biasH, int* __restrict__ labels,
                       u16* __restrict__ Zcat16){
    __shared__ float sh[32 * 33];
    int blk = blockIdx.x;
    int tid = threadIdx.x;
    if (blk < 912){
        int b   = blk / 456;           // 19*24
        int rem = blk % 456;
        int cb  = rem / 19, sb = rem % 19;
        int tx = tid & 31, ty = tid >> 5;      // 32 x 8
        int s0 = sb * 32, c0 = cb * 32;
        float (*tile)[33] = (float(*)[33])sh;
        #pragma unroll
        for (int i = 0; i < 4; i++){
            int c = c0 + ty + i * 8;
            int s = s0 + tx;
            if (s < 577) tile[ty + i * 8][tx] = noise[(size_t)(b * 768 + c) * 577 + s];
        }
        __syncthreads();
        #pragma unroll
        for (int i = 0; i < 4; i++){
            int s = s0 + ty + i * 8;
            int c = c0 + tx;
            if (s >= 577) continue;
            float v = tile[tx][ty + i * 8];
            out0[(size_t)(s * 2 + b) * 768 + c] = v;
            if (s >= 1) XbfT[(size_t)(b * 576 + s - 1) * 768 + c] = f2bf(v);
        }
    } else if (blk < 2448){
        int idx = (blk - 912) * 256 + tid;     // < 512*768
        int k = idx % 768; int c1 = idx / 768;
        const float* wp = w1 + (size_t)idx * 9;
        #pragma unroll
        for (int tap = 0; tap < 9; tap++)
            Are[(size_t)(c1 * 9 + tap) * 768 + k] = f2bf(wp[tap]);
    } else if (blk < 3472){
        // Mfull16 + bias partial: block b2i = blk-2448 covers c2 = b2i>>1, c1-half h = b2i&1
        int b2i = blk - 2448;
        int c2 = b2i >> 1, h = b2i & 1;
        int c1 = h * 256 + tid;
        const float* wp = w2 + (size_t)(c2 * 512 + c1) * 9;
        float t[3][3];
        #pragma unroll
        for (int r = 0; r < 3; r++)
            #pragma unroll
            for (int s = 0; s < 3; s++)
                t[r][s] = wp[r * 3 + s];
        float cs0[3], cs1[3], cs2[3];
        #pragma unroll
        for (int r = 0; r < 3; r++){
            cs0[r] = t[r][0] + t[r][1];
            cs1[r] = t[r][0] + t[r][1] + t[r][2];
            cs2[r] = t[r][1] + t[r][2];
        }
        const float inv = 1.0f / 576.0f;
        u16* Mp = Mfull16 + (size_t)(c2 * 512 + c1) * 9;
        Mp[0] = f2bf(inv * (cs0[0] + cs0[1]));
        Mp[1] = f2bf(inv * (cs1[0] + cs1[1]));
        Mp[2] = f2bf(inv * (cs2[0] + cs2[1]));
        Mp[3] = f2bf(inv * (cs0[0] + cs0[1] + cs0[2]));
        Mp[4] = f2bf(inv * (cs1[0] + cs1[1] + cs1[2]));
        Mp[5] = f2bf(inv * (cs2[0] + cs2[1] + cs2[2]));
        Mp[6] = f2bf(inv * (cs0[1] + cs0[2]));
        Mp[7] = f2bf(inv * (cs1[1] + cs1[2]));
        Mp[8] = f2bf(inv * (cs2[1] + cs2[2]));
        // bias partial: sum_{c1 in half} b1[c1] * (sum_q w2[q]*cw[q]) / 36
        float s_cw = 25.f * (t[0][0] + t[0][2] + t[2][0] + t[2][2])
                   + 30.f * (t[0][1] + t[1][0] + t[1][2] + t[2][1])
                   + 36.f * t[1][1];
        sh[tid] = b1[c1] * s_cw;
        __syncthreads();
        for (int o = 128; o > 0; o >>= 1){ if (tid < o) sh[tid] += sh[tid + o]; __syncthreads(); }
        if (tid == 0) biasH[h * 512 + c2] = sh[0] * (1.0f / 36.0f);
    } else if (blk < 3477){
        int idx = (blk - 3472) * 256 + tid;
        if (idx < 1152){
            int b = idx / 576; int p = idx % 576;
            int i = p / 24, j = p % 24;
            labels[idx] = targets[b * 147456 + i * 16 * 384 + j * 16];
        }
    } else {
        // zero Zcat pad rows 342..383 (42*4608 = 193536 u16)
        int idx = (blk - 3477) * 256 + tid;
        if (idx < 193536) Zcat16[342 * 4608 + idx] = 0;
    }
}

// ---------------- GEMM1 v3: 192x128 tile, LDS double-buffer, counted vmcnt, XOR-swizzle ----
// D[4608][1152] (bf16) = Are * XbfT^T.  Grid (24,9) = 216 blocks, single dispatch round.
// Swizzle (T2, rule #21): pre-swizzled global source, linear LDS dest, same XOR on read.
// Pipeline (T3/T4 minimum form): stage(t+1) before compute(t); counted vmcnt, raw s_barrier.
// NO setprio here: 2-barrier lockstep regime, T5 measured negative (m190).
__launch_bounds__(256)
__global__ void k_gemm1(const u16* __restrict__ Are, const u16* __restrict__ XbfT,
                        u16* __restrict__ D){
    __shared__ u16 As[2][192 * 64];   // 24 KB x2
    __shared__ u16 Bs[2][128 * 64];   // 16 KB x2  (total 80 KB -> 2 blocks/CU)
    int tid  = threadIdx.x;
    int wave = tid >> 6, lane = tid & 63;
    int l16 = lane & 15, quad = lane >> 4;
    int wm = wave >> 1, wn = wave & 1;      // 2x2 waves; wave-tile 96x64
    int m0 = blockIdx.x * 192;
    int n0 = blockIdx.y * 128;
    int srow = lane >> 3;                           // 0..7 (row within 8-row chunk)
    int scol = ((lane & 7) * 8) ^ (srow * 8);       // pre-swizzled source col (u16 units)
    int rx   = (l16 & 7) * 8;                       // read-side XOR
    const u16* Ag = Are  + (size_t)(m0 + srow) * 768 + scol;
    const u16* Bg = XbfT + (size_t)(n0 + srow) * 768 + scol;
    f32x4 acc[6][4] = {};

    auto stage = [&](int buf, int k0){
        #pragma unroll
        for (int j = 0; j < 6; j++){
            int ch = wave * 6 + j;                  // 24 A-chunks of 8 rows
            gload_lds16(Ag + (size_t)ch * 8 * 768 + k0, &As[buf][ch * 512]);
        }
        #pragma unroll
        for (int j = 0; j < 4; j++){
            int ch = wave * 4 + j;                  // 16 B-chunks of 8 rows
            gload_lds16(Bg + (size_t)ch * 8 * 768 + k0, &Bs[buf][ch * 512]);
        }
    };
    auto compute = [&](int buf){
        #pragma unroll
        for (int ks = 0; ks < 2; ks++){
            int kc = (ks * 32 + quad * 8) ^ rx;
            bf16x8 af[6], bf[4];
            #pragma unroll
            for (int i = 0; i < 6; i++)
                af[i] = *(const bf16x8*)&As[buf][(wm * 96 + i * 16 + l16) * 64 + kc];
            #pragma unroll
            for (int i = 0; i < 4; i++)
                bf[i] = *(const bf16x8*)&Bs[buf][(wn * 64 + i * 16 + l16) * 64 + kc];
            #pragma unroll
            for (int mi = 0; mi < 6; mi++)
                #pragma unroll
                for (int ni = 0; ni < 4; ni++)
                    acc[mi][ni] = __builtin_amdgcn_mfma_f32_16x16x32_bf16(af[mi], bf[ni], acc[mi][ni], 0, 0, 0);
        }
    };

    stage(0, 0);
    #pragma unroll 1
    for (int t = 0; t < 10; t += 2){
        stage(1, (t + 1) * 64);
        asm volatile("s_waitcnt vmcnt(10)" ::: "memory");
        wgbar();
        compute(0);
        wgbar();
        stage(0, (t + 2) * 64);
        asm volatile("s_waitcnt vmcnt(10)" ::: "memory");
        wgbar();
        compute(1);
        wgbar();
    }
    stage(1, 11 * 64);
    asm volatile("s_waitcnt vmcnt(10)" ::: "memory");
    wgbar();
    compute(0);                 // K-step 10
    wgbar();
    asm volatile("s_waitcnt vmcnt(0)" ::: "memory");
    wgbar();
    compute(1);                 // K-step 11

    #pragma unroll
    for (int mi = 0; mi < 6; mi++)
        #pragma unroll
        for (int ni = 0; ni < 4; ni++)
            #pragma unroll
            for (int r = 0; r < 4; r++)
                D[(size_t)(m0 + wm * 96 + mi * 16 + quad * 4 + r) * 1152 + n0 + wn * 64 + ni * 16 + l16] = f2bf(acc[mi][ni][r]);
}

// ---------------- scatter: one block per (b,c1); LDS class-histogram; bf16 in/out --------
__launch_bounds__(256)
__global__ void k_scatter(const u16* __restrict__ D, const int* __restrict__ labels,
                          u16* __restrict__ Zcat16){
    int blk = blockIdx.x;            // 0..1023
    int b  = blk >> 9;
    int c1 = blk & 511;
    __shared__ float acc[171 * 9];
    int t = threadIdx.x;
    for (int q = t; q < 1539; q += 256) acc[q] = 0.f;
    __syncthreads();
    for (int p = t; p < 576; p += 256){
        int cls = labels[b * 576 + p];
        if (cls < 0 || cls >= 171) continue;
        int i = p / 24, j = p % 24;
        float slot[9];
        #pragma unroll
        for (int q = 0; q < 9; q++) slot[q] = 0.f;
        unsigned used = 0;
        int tau[3]; bool vs[3];
        #pragma unroll
        for (int s1 = 0; s1 < 3; s1++){
            int v = j - s1 + 1;
            vs[s1]  = (v >= 0 && v < 24);
            tau[s1] = (v < 4) ? 0 : ((v < 20) ? 1 : 2);
        }
        #pragma unroll
        for (int r1 = 0; r1 < 3; r1++){
            int u = i - r1 + 1;
            if (u < 0 || u >= 24) continue;
            int rho = (u < 4) ? 0 : ((u < 20) ? 1 : 2);
            #pragma unroll
            for (int s1 = 0; s1 < 3; s1++){
                if (!vs[s1]) continue;
                float tv = bf2f(D[(size_t)(c1 * 9 + r1 * 3 + s1) * 1152 + b * 576 + p]);
                int sl = rho * 3 + tau[s1];
                slot[sl] += tv;
                used |= 1u << sl;
            }
        }
        #pragma unroll
        for (int sl = 0; sl < 9; sl++)
            if (used & (1u << sl)) atomicAdd(&acc[cls * 9 + sl], slot[sl]);
    }
    __syncthreads();
    for (int q = t; q < 1539; q += 256){
        int cls = q / 9, sl = q % 9;
        Zcat16[(size_t)(b * 171 + cls) * 4608 + c1 * 9 + sl] = f2bf(acc[q]);
    }
}

// ---------------- GEMM2 (LDS-staged MFMA, K-split): ypart[s][n][c2] ----------------
// A = Zcat16[384][4608] (rows n, 128-tile), B = Mfull16[512][4608] (rows c2, 64-tile).
// Output rows = n, cols = c2 -> coalesced stores. Grid (3, 8, KS2), K-chunk 384.
// Deterministic ypart + k_red reduction (R4's atomic variant measured +4.3 us;
// R6's fused reduce+expand measured +9.9 us — keep the split, TLP on the store path).
__launch_bounds__(256)
__global__ void k_gemm2m(const u16* __restrict__ Zcat16, const u16* __restrict__ Mfull16,
                         float* __restrict__ ypart){
    __shared__ u16 As[128 * 64];   // [n][k]
    __shared__ u16 Bs[64 * 64];    // [c2][k]
    int tid  = threadIdx.x;
    int wave = tid >> 6, lane = tid & 63;
    int l16 = lane & 15, quad = lane >> 4;
    int wm = wave >> 1, wn = wave & 1;
    int m0 = blockIdx.x * 128;          // n
    int n0 = blockIdx.y * 64;           // c2
    int kbeg = blockIdx.z * 384;
    int srow = lane >> 3, scol = (lane & 7) * 8;
    f32x4 acc[4][2] = {};
    for (int k0 = kbeg; k0 < kbeg + 384; k0 += 64){
        #pragma unroll
        for (int j = 0; j < 4; j++){
            int ch = wave * 4 + j;
            gload_lds16(Zcat16 + (size_t)(m0 + ch * 8 + srow) * 4608 + k0 + scol, &As[ch * 512]);
        }
        #pragma unroll
        for (int j = 0; j < 2; j++){
            int ch = wave * 2 + j;
            gload_lds16(Mfull16 + (size_t)(n0 + ch * 8 + srow) * 4608 + k0 + scol, &Bs[ch * 512]);
        }
        __syncthreads();
        #pragma unroll
        for (int ks = 0; ks < 2; ks++){
            bf16x8 af[4], bf[2];
            #pragma unroll
            for (int i = 0; i < 4; i++)
                af[i] = *(const bf16x8*)&As[(wm * 64 + i * 16 + l16) * 64 + ks * 32 + quad * 8];
            #pragma unroll
            for (int i = 0; i < 2; i++)
                bf[i] = *(const bf16x8*)&Bs[(wn * 32 + i * 16 + l16) * 64 + ks * 32 + quad * 8];
            #pragma unroll
            for (int mi = 0; mi < 4; mi++)
                #pragma unroll
                for (int ni = 0; ni < 2; ni++)
                    acc[mi][ni] = __builtin_amdgcn_mfma_f32_16x16x32_bf16(af[mi], bf[ni], acc[mi][ni], 0, 0, 0);
        }
        __syncthreads();
    }
    float* yp = ypart + (size_t)blockIdx.z * YN;
    #pragma unroll
    for (int mi = 0; mi < 4; mi++)
        #pragma unroll
        for (int r = 0; r < 4; r++){
            int n = m0 + wm * 64 + mi * 16 + quad * 4 + r;
            if (n >= 342) continue;
            #pragma unroll
            for (int ni = 0; ni < 2; ni++)
                yp[(size_t)n * 512 + n0 + wn * 32 + ni * 16 + l16] = acc[mi][ni][r];
        }
}

// ---------------- reduce: ysum[n][c] = b2[c] + biasH[0][c] + biasH[1][c] + sum_s ypart ----
// 342 blocks x 128 threads = 43776 float4 items (YN/4)
__global__ void k_red(const float* __restrict__ ypart, const float* __restrict__ biasH,
                      const float* __restrict__ b2, float4* __restrict__ ysum){
    int idx = blockIdx.x * 128 + threadIdx.x;   // < YN/4
    int c4 = idx & 127;
    int n  = idx >> 7;
    float4 sum = ((const float4*)b2)[c4];
    float4 ba  = ((const float4*)biasH)[c4];
    float4 bb  = ((const float4*)biasH)[128 + c4];
    sum.x += ba.x + bb.x; sum.y += ba.y + bb.y; sum.z += ba.z + bb.z; sum.w += ba.w + bb.w;
    #pragma unroll
    for (int s = 0; s < KS2; s++){
        float4 v = *(const float4*)&ypart[(size_t)s * YN + (size_t)n * 512 + c4 * 4];
        sum.x += v.x; sum.y += v.y; sum.z += v.z; sum.w += v.w;
    }
    ysum[idx] = sum;
}

// ---------------- expand: out1[b,o,cls,c] = w3[o]*ysum[b,cls,c] + b3[o] ----------------
// pure write-bound: 13167 blocks x 256 threads, one coalesced float4 store each.
// Max TLP on the 54 MB output write — R6's 684-block fused variant cost +9.9 us.
__global__ void k_expand(const float4* __restrict__ ysum, const float* __restrict__ w3,
                         const float* __restrict__ b3, float4* __restrict__ out1){
    int idx = blockIdx.x * 256 + threadIdx.x;   // < OUT1_N/4 = 3370752
    if (idx >= OUT1_N / 4) return;
    int c4 = idx & 127;
    int t  = idx >> 7;                 // (b*77 + o)*171 + cls
    int cls = t % 171;
    int u   = t / 171;                 // b*77 + o
    int o   = u % 77;
    int b   = u / 77;
    float w  = w3[o];
    float bb = b3[o];
    float4 v = ysum[(b * 171 + cls) * 128 + c4];
    out1[idx] = make_float4(w * v.x + bb, w * v.y + bb, w * v.z + bb, w * v.w + bb);
}

extern "C" void kernel_launch(void* const* d_in, const int* in_sizes, int n_in,
                              void* d_out, int out_size, void* d_ws, size_t ws_size,
                              hipStream_t stream) {
    const float* noise   = (const float*)d_in[0];
    const int*   targets = (const int*)  d_in[1];
    const float* w1      = (const float*)d_in[2];
    const float* b1      = (const float*)d_in[3];
    const float* w2      = (const float*)d_in[4];
    const float* b2      = (const float*)d_in[5];
    const float* w3      = (const float*)d_in[6];
    const float* b3      = (const float*)d_in[7];
    float* out0 = (float*)d_out;
    float* out1 = out0 + OUT0_N;

    char* ws = (char*)d_ws;
    const size_t OFF_ARE  = 0;                        // 4608*768*2   = 7,077,888
    const size_t OFF_X    = 7077888;                  // 1152*768*2   = 1,769,472
    const size_t OFF_D    = OFF_X   + 1769472;        // 4608*1152*2  = 10,616,832 (bf16; alias ypart 8,404,992)
    const size_t OFF_MF   = OFF_D   + 10616832;       // 512*4608*2   = 4,718,592
    const size_t OFF_ZC   = OFF_MF  + 4718592;        // 384*4608*2   = 3,538,944
    const size_t OFF_BH   = OFF_ZC  + 3538944;        // 2*512*4 = 4096
    const size_t OFF_LAB  = OFF_BH  + 4096;           // 4608
    const size_t OFF_YS   = OFF_LAB + 4608;           // 342*512*4    = 700,416

    u16*   Are    = (u16*)  (ws + OFF_ARE);
    u16*   XbfT   = (u16*)  (ws + OFF_X);
    u16*   D      = (u16*)  (ws + OFF_D);
    float* ypart  = (float*)(ws + OFF_D);             // alias: D dead after k_scatter; 8.4MB <= 10.6MB
    u16*   Mfull16= (u16*)  (ws + OFF_MF);
    u16*   Zcat16 = (u16*)  (ws + OFF_ZC);
    float* biasH  = (float*)(ws + OFF_BH);
    int*   labels = (int*)  (ws + OFF_LAB);
    float* ysum   = (float*)(ws + OFF_YS);

    k_prep  <<<4233, 256, 0, stream>>>(noise, targets, w1, b1, w2,
                                       out0, XbfT, Are, Mfull16, biasH, labels, Zcat16);
    k_gemm1 <<<dim3(24, 9), 256, 0, stream>>>(Are, XbfT, D);
    k_scatter<<<1024, 256, 0, stream>>>(D, labels, Zcat16);
    k_gemm2m<<<dim3(3, 8, KS2), 256, 0, stream>>>(Zcat16, Mfull16, ypart);
    k_red   <<<342, 128, 0, stream>>>(ypart, biasH, b2, (float4*)ysum);
    k_expand<<<13167, 256, 0, stream>>>((const float4*)ysum, w3, b3, (float4*)out1);
}